// Round 1
// baseline (439.094 us; speedup 1.0000x reference)
//
#include <hip/hip_runtime.h>
#include <hip/hip_bf16.h>
#include <stdint.h>

typedef __hip_bfloat16 bf16;
typedef __attribute__((ext_vector_type(8))) short short8;
typedef __attribute__((ext_vector_type(4))) float f32x4;

#define NTOK  4096      // B*T
#define EDIM  1024
#define NEXPT 8
#define INTERD 1408
#define MAXP  4096      // max tokens routed to one expert
#define BM 64
#define BN 64
#define BK 32
#define RS 40           // LDS row stride (elems): 32 data + 8 pad -> 2-way bank aliasing only

// ---------------- fp32 -> bf16 conversion (vectorized, grid-stride) ----------------
__global__ __launch_bounds__(256) void cvt_kernel(const float* __restrict__ src,
                                                  bf16* __restrict__ dst, int n) {
    int i = (blockIdx.x * 256 + threadIdx.x) * 4;
    int stride = gridDim.x * 256 * 4;
    for (; i < n; i += stride) {
        float4 v = *(const float4*)(src + i);
        ushort4 o;
        bf16 b;
        b = __float2bfloat16(v.x); o.x = *(unsigned short*)&b;
        b = __float2bfloat16(v.y); o.y = *(unsigned short*)&b;
        b = __float2bfloat16(v.z); o.z = *(unsigned short*)&b;
        b = __float2bfloat16(v.w); o.w = *(unsigned short*)&b;
        *(ushort4*)(dst + i) = o;
    }
}

// ---------------- router: scores -> top2 -> softmax -> scatter to expert buckets ----
__global__ __launch_bounds__(64) void router_kernel(const float* __restrict__ x,
                                                    const float* __restrict__ gw,
                                                    int* __restrict__ counts,
                                                    int* __restrict__ ptok,
                                                    float* __restrict__ pprob) {
    int t = blockIdx.x;
    int lane = threadIdx.x;
    const float* xr = x + (size_t)t * EDIM;
    // double accumulation -> near-exact scores so top-2 selection matches numpy ref
    double acc[NEXPT];
#pragma unroll
    for (int e = 0; e < NEXPT; e++) acc[e] = 0.0;
    for (int d = lane; d < EDIM; d += 64) {
        float xv = xr[d];
#pragma unroll
        for (int e = 0; e < NEXPT; e++) acc[e] += (double)xv * (double)gw[e * EDIM + d];
    }
#pragma unroll
    for (int off = 32; off >= 1; off >>= 1) {
#pragma unroll
        for (int e = 0; e < NEXPT; e++) acc[e] += __shfl_xor(acc[e], off, 64);
    }
    if (lane == 0) {
        int e0 = 0; double s0 = acc[0];
        for (int e = 1; e < NEXPT; e++) if (acc[e] > s0) { s0 = acc[e]; e0 = e; }
        int e1 = -1; double s1 = -1e300;
        for (int e = 0; e < NEXPT; e++) if (e != e0 && acc[e] > s1) { s1 = acc[e]; e1 = e; }
        float z = __expf((float)(s1 - s0));
        float p0 = 1.f / (1.f + z);
        float p1 = 1.f - p0;
        int pos0 = atomicAdd(&counts[e0], 1);
        ptok[e0 * MAXP + pos0] = t; pprob[e0 * MAXP + pos0] = p0;
        int pos1 = atomicAdd(&counts[e1], 1);
        ptok[e1 * MAXP + pos1] = t; pprob[e1 * MAXP + pos1] = p1;
    }
}

__global__ void scan_kernel(const int* __restrict__ counts, int* __restrict__ offsets) {
    if (threadIdx.x == 0 && blockIdx.x == 0) {
        int s = 0;
        for (int e = 0; e < NEXPT; e++) { offsets[e] = s; s += counts[e]; }
    }
}

// ---------------- GEMM1: h = silu(x@wg^T) * (x@wu^T)  (gathered rows) ----------------
__global__ __launch_bounds__(256) void gemm1_kernel(const bf16* __restrict__ xb,
                                                    const bf16* __restrict__ wgb,
                                                    const bf16* __restrict__ wub,
                                                    bf16* __restrict__ hout,
                                                    const int* __restrict__ counts,
                                                    const int* __restrict__ offsets,
                                                    const int* __restrict__ ptok) {
    int e = blockIdx.x >> 6;          // MAXP/BM = 64 m-tiles per expert
    int mt = blockIdx.x & 63;
    int cnt = counts[e];
    int m0 = mt * BM;
    if (m0 >= cnt) return;
    int n0 = blockIdx.y * BN;         // over INTER (22 tiles)

    __shared__ __align__(16) bf16 sA[BM * RS];
    __shared__ __align__(16) bf16 sBg[BN * RS];
    __shared__ __align__(16) bf16 sBu[BN * RS];

    int tid = threadIdx.x;
    int lane = tid & 63;
    int wid = tid >> 6;
    int wm = wid >> 1, wn = wid & 1;  // 2x2 wave grid over 64x64

    // staging: thread -> (row 0..63, 16B chunk 0..3)
    int srow = tid >> 2;
    int schk = tid & 3;
    int apos = m0 + srow;
    bool avalid = apos < cnt;
    int atok = avalid ? ptok[e * MAXP + apos] : 0;
    const bf16* aptr = xb + (size_t)atok * EDIM + schk * 8;
    const bf16* gptr = wgb + ((size_t)e * INTERD + n0 + srow) * EDIM + schk * 8;
    const bf16* uptr = wub + ((size_t)e * INTERD + n0 + srow) * EDIM + schk * 8;
    int swoff = srow * RS + schk * 8;

    f32x4 accg[2][2], accu[2][2];
#pragma unroll
    for (int m = 0; m < 2; m++)
#pragma unroll
        for (int n = 0; n < 2; n++) {
            accg[m][n] = (f32x4){0.f, 0.f, 0.f, 0.f};
            accu[m][n] = (f32x4){0.f, 0.f, 0.f, 0.f};
        }

    int arow0 = wm * 32 + (lane & 15);
    int brow0 = wn * 32 + (lane & 15);
    int krd = (lane >> 4) * 8;

    for (int k0 = 0; k0 < EDIM; k0 += BK) {
        uint4 av = {0, 0, 0, 0};
        if (avalid) av = *(const uint4*)aptr;
        uint4 gv = *(const uint4*)gptr;
        uint4 uv = *(const uint4*)uptr;
        aptr += BK; gptr += BK; uptr += BK;
        __syncthreads();
        *(uint4*)&sA[swoff] = av;
        *(uint4*)&sBg[swoff] = gv;
        *(uint4*)&sBu[swoff] = uv;
        __syncthreads();
        short8 a[2], g[2], u[2];
#pragma unroll
        for (int m = 0; m < 2; m++) a[m] = *(const short8*)&sA[(arow0 + m * 16) * RS + krd];
#pragma unroll
        for (int n = 0; n < 2; n++) {
            g[n] = *(const short8*)&sBg[(brow0 + n * 16) * RS + krd];
            u[n] = *(const short8*)&sBu[(brow0 + n * 16) * RS + krd];
        }
#pragma unroll
        for (int m = 0; m < 2; m++)
#pragma unroll
            for (int n = 0; n < 2; n++) {
                accg[m][n] = __builtin_amdgcn_mfma_f32_16x16x32_bf16(a[m], g[n], accg[m][n], 0, 0, 0);
                accu[m][n] = __builtin_amdgcn_mfma_f32_16x16x32_bf16(a[m], u[n], accu[m][n], 0, 0, 0);
            }
    }

    int hbase = offsets[e];
#pragma unroll
    for (int m = 0; m < 2; m++)
#pragma unroll
        for (int n = 0; n < 2; n++)
#pragma unroll
            for (int r = 0; r < 4; r++) {
                int pos = m0 + wm * 32 + m * 16 + (lane >> 4) * 4 + r;
                if (pos < cnt) {
                    int col = n0 + wn * 32 + n * 16 + (lane & 15);
                    float gv = accg[m][n][r];
                    float uv = accu[m][n][r];
                    float hv = (gv / (1.f + __expf(-gv))) * uv;
                    hout[(size_t)(hbase + pos) * INTERD + col] = __float2bfloat16(hv);
                }
            }
}

// ---------------- GEMM2: y[t] += prob * (h @ wd^T) ----------------
__global__ __launch_bounds__(256) void gemm2_kernel(const bf16* __restrict__ h,
                                                    const bf16* __restrict__ wdb,
                                                    float* __restrict__ y,
                                                    const int* __restrict__ counts,
                                                    const int* __restrict__ offsets,
                                                    const int* __restrict__ ptok,
                                                    const float* __restrict__ pprob) {
    int e = blockIdx.x >> 6;
    int mt = blockIdx.x & 63;
    int cnt = counts[e];
    int m0 = mt * BM;
    if (m0 >= cnt) return;
    int n0 = blockIdx.y * BN;         // over E (16 tiles)

    __shared__ __align__(16) bf16 sA[BM * RS];
    __shared__ __align__(16) bf16 sB[BN * RS];

    int tid = threadIdx.x;
    int lane = tid & 63;
    int wid = tid >> 6;
    int wm = wid >> 1, wn = wid & 1;

    int srow = tid >> 2;
    int schk = tid & 3;
    int apos = m0 + srow;
    bool avalid = apos < cnt;
    int hbase = offsets[e];
    const bf16* aptr = h + (size_t)(hbase + (avalid ? apos : 0)) * INTERD + schk * 8;
    const bf16* bptr = wdb + ((size_t)e * EDIM + n0 + srow) * INTERD + schk * 8;
    int swoff = srow * RS + schk * 8;

    f32x4 acc[2][2];
#pragma unroll
    for (int m = 0; m < 2; m++)
#pragma unroll
        for (int n = 0; n < 2; n++) acc[m][n] = (f32x4){0.f, 0.f, 0.f, 0.f};

    int arow0 = wm * 32 + (lane & 15);
    int brow0 = wn * 32 + (lane & 15);
    int krd = (lane >> 4) * 8;

    for (int k0 = 0; k0 < INTERD; k0 += BK) {
        uint4 av = {0, 0, 0, 0};
        if (avalid) av = *(const uint4*)aptr;
        uint4 bv = *(const uint4*)bptr;
        aptr += BK; bptr += BK;
        __syncthreads();
        *(uint4*)&sA[swoff] = av;
        *(uint4*)&sB[swoff] = bv;
        __syncthreads();
        short8 a[2], b[2];
#pragma unroll
        for (int m = 0; m < 2; m++) a[m] = *(const short8*)&sA[(arow0 + m * 16) * RS + krd];
#pragma unroll
        for (int n = 0; n < 2; n++) b[n] = *(const short8*)&sB[(brow0 + n * 16) * RS + krd];
#pragma unroll
        for (int m = 0; m < 2; m++)
#pragma unroll
            for (int n = 0; n < 2; n++)
                acc[m][n] = __builtin_amdgcn_mfma_f32_16x16x32_bf16(a[m], b[n], acc[m][n], 0, 0, 0);
    }

#pragma unroll
    for (int m = 0; m < 2; m++)
#pragma unroll
        for (int n = 0; n < 2; n++)
#pragma unroll
            for (int r = 0; r < 4; r++) {
                int pos = m0 + wm * 32 + m * 16 + (lane >> 4) * 4 + r;
                if (pos < cnt) {
                    int t = ptok[e * MAXP + pos];
                    float p = pprob[e * MAXP + pos];
                    int col = n0 + wn * 32 + n * 16 + (lane & 15);
                    atomicAdd(&y[(size_t)t * EDIM + col], p * acc[m][n][r]);
                }
            }
}

// ---------------- launch ----------------
extern "C" void kernel_launch(void* const* d_in, const int* in_sizes, int n_in,
                              void* d_out, int out_size, void* d_ws, size_t ws_size,
                              hipStream_t stream) {
    const float* x      = (const float*)d_in[0];
    const float* gate_w = (const float*)d_in[1];
    const float* wg     = (const float*)d_in[2];
    const float* wu     = (const float*)d_in[3];
    const float* wd     = (const float*)d_in[4];
    float* y = (float*)d_out;

    char* ws = (char*)d_ws;
    constexpr size_t SZ_XB = (size_t)NTOK * EDIM * 2;
    constexpr size_t SZ_W  = (size_t)NEXPT * INTERD * EDIM * 2;
    constexpr size_t SZ_H  = (size_t)NTOK * 2 * INTERD * 2;
    bf16* xb  = (bf16*)ws;
    bf16* wgb = (bf16*)(ws + SZ_XB);
    bf16* wub = (bf16*)(ws + SZ_XB + SZ_W);
    bf16* wdb = (bf16*)(ws + SZ_XB + 2 * SZ_W);
    bf16* h   = (bf16*)(ws + SZ_XB + 3 * SZ_W);
    char* meta = ws + SZ_XB + 3 * SZ_W + SZ_H;
    int*   counts  = (int*)meta;
    int*   offsets = (int*)(meta + 256);
    int*   ptok    = (int*)(meta + 512);
    float* pprob   = (float*)(meta + 512 + (size_t)NEXPT * MAXP * 4);

    // zero outputs (we accumulate with atomics) and bucket counts
    hipMemsetAsync(d_out, 0, (size_t)out_size * 4, stream);
    hipMemsetAsync(counts, 0, 256, stream);

    cvt_kernel<<<2048, 256, 0, stream>>>(x,  xb,  NTOK * EDIM);
    cvt_kernel<<<2048, 256, 0, stream>>>(wg, wgb, NEXPT * INTERD * EDIM);
    cvt_kernel<<<2048, 256, 0, stream>>>(wu, wub, NEXPT * INTERD * EDIM);
    cvt_kernel<<<2048, 256, 0, stream>>>(wd, wdb, NEXPT * EDIM * INTERD);

    router_kernel<<<NTOK, 64, 0, stream>>>(x, gate_w, counts, ptok, pprob);
    scan_kernel<<<1, 64, 0, stream>>>(counts, offsets);

    gemm1_kernel<<<dim3(NEXPT * (MAXP / BM), INTERD / BN), 256, 0, stream>>>(
        xb, wgb, wub, h, counts, offsets, ptok);
    gemm2_kernel<<<dim3(NEXPT * (MAXP / BM), EDIM / BN), 256, 0, stream>>>(
        h, wdb, y, counts, offsets, ptok, pprob);
}